// Round 6
// baseline (55.554 us; speedup 1.0000x reference)
//
#include <hip/hip_runtime.h>
#include <hip/hip_bf16.h>

// B=8, H=64, W=64, C=256, NUM_HEADS=8, dph=32, DIL=3, k2=9
// qkv GEMM: Y[32768,768] = X[32768,256](f32, staged direct) @ W[768,256]^T (bf16).
// ws layout (ushort units): wb[196608] | qkv[25165824]

typedef unsigned short ushortT;
typedef __attribute__((ext_vector_type(8))) short short8;
typedef __attribute__((ext_vector_type(4))) float f32x4;
typedef __attribute__((ext_vector_type(4))) unsigned int u32x4;

__device__ __forceinline__ ushortT f2b(float f) {  // RTNE f32 -> bf16 bits
    unsigned u = __float_as_uint(f);
    return (ushortT)((u + 0x7fffu + ((u >> 16) & 1u)) >> 16);
}
__device__ __forceinline__ float b2f(ushortT u) {
    return __uint_as_float((unsigned)u << 16);
}
__device__ __forceinline__ unsigned cvtpk(float a, float b) {  // [lo=a, hi=b] bf16 pair, RTNE
    unsigned r;
    asm("v_cvt_pk_bf16_f32 %0, %1, %2" : "=v"(r) : "v"(a), "v"(b));
    return r;
}

// ---- convert W [196608 f32] to bf16 (x is consumed f32 directly by the GEMM) ----
__global__ __launch_bounds__(256) void wcvt(const float* __restrict__ wq,
                                            ushortT* __restrict__ wb) {
    int i = blockIdx.x * 256 + threadIdx.x;  // 0..49151 float4s
    float4 f = ((const float4*)wq)[i];
    ushort4 u = {f2b(f.x), f2b(f.y), f2b(f.z), f2b(f.w)};
    ((ushort4*)wb)[i] = u;
}

// ---- bf16 MFMA GEMM, A staged as f32: 128x128 tile, BK=64, 4 waves (2x2) ----
// As: [128 rows][16 slots of 16B] f32 (32KB), XOR swizzle slot^(row&15) via source addr.
// Bs: [128 rows][8 slots of 16B] bf16 (16KB), swizzle slot^(row&7).
// A fragments converted f32->bf16 in-register with v_cvt_pk_bf16_f32.
// Epilogue: repack C through As region (32KB = 128x128 bf16) -> coalesced 16B stores.
__global__ __launch_bounds__(256) void gemm_qkv(const float* __restrict__ A,
                                                const ushortT* __restrict__ Bw,
                                                ushortT* __restrict__ Y) {
    __shared__ __align__(16) ushortT smem[24576];  // 48KB
    float* Af = (float*)smem;                      // [128][64] f32
    ushortT* Bs = smem + 16384;                    // [128][64] bf16

    // XCD-chunked swizzle: 1536 blocks, 8 XCDs, 192 per XCD (bijective).
    int bid = blockIdx.x;
    int swz = (bid & 7) * 192 + (bid >> 3);
    int mblk = swz / 6, nblk = swz - mblk * 6;
    const int m0 = mblk * 128, n0 = nblk * 128;

    const int t = threadIdx.x;
    const int lane = t & 63, wv = t >> 6;
    const int wm = (wv >> 1) * 64, wn = (wv & 1) * 64;
    const int lr = lane & 15, g = lane >> 4;
    const int srow = t >> 3, sslot = t & 7;  // B staging: 32 rows/pass, 8 slots
    const int arow = t >> 4, aslot = t & 15; // A staging: 16 rows/pass, 16 slots
    const int wvbase = (t & ~63) * 8;        // wave-uniform LDS base (ushort units)

    f32x4 acc[4][4] = {};

    for (int k0 = 0; k0 < 256; k0 += 64) {
        __syncthreads();
        // A: 8 passes x 4KB, f32. LDS dest linear; source slot inverse-swizzled.
#pragma unroll
        for (int p = 0; p < 8; ++p) {
            int row = p * 16 + arow;
            int ss = aslot ^ (row & 15);
            const float* ga = A + (size_t)(m0 + row) * 256 + k0 + ss * 4;
            __builtin_amdgcn_global_load_lds(
                (const __attribute__((address_space(1))) unsigned int*)ga,
                (__attribute__((address_space(3))) unsigned int*)(smem + p * 2048 + wvbase),
                16, 0, 0);
        }
        // B: 4 passes x 4KB, bf16.
#pragma unroll
        for (int r = 0; r < 4; ++r) {
            int row = r * 32 + srow;
            int ss = sslot ^ (row & 7);
            const ushortT* gb = Bw + (size_t)(n0 + row) * 256 + k0 + ss * 8;
            __builtin_amdgcn_global_load_lds(
                (const __attribute__((address_space(1))) unsigned int*)gb,
                (__attribute__((address_space(3))) unsigned int*)(Bs + r * 2048 + wvbase),
                16, 0, 0);
        }
        __syncthreads();  // compiler drains vmcnt before barrier

#pragma unroll
        for (int ksub = 0; ksub < 2; ++ksub) {
            short8 af[4], bfr[4];
#pragma unroll
            for (int mi = 0; mi < 4; ++mi) {
                int row = wm + mi * 16 + lr;
                int jb = 2 * (ksub * 4 + g);
                int s0 = jb ^ (row & 15);
                int s1 = (jb + 1) ^ (row & 15);
                f32x4 lo = *(const f32x4*)&Af[row * 64 + s0 * 4];
                f32x4 hi = *(const f32x4*)&Af[row * 64 + s1 * 4];
                u32x4 pk;
                pk[0] = cvtpk(lo[0], lo[1]);
                pk[1] = cvtpk(lo[2], lo[3]);
                pk[2] = cvtpk(hi[0], hi[1]);
                pk[3] = cvtpk(hi[2], hi[3]);
                af[mi] = __builtin_bit_cast(short8, pk);
            }
#pragma unroll
            for (int ni = 0; ni < 4; ++ni) {
                int row = wn + ni * 16 + lr;
                int slot = (ksub * 4 + g) ^ (row & 7);
                bfr[ni] = *(const short8*)&Bs[row * 64 + slot * 8];
            }
#pragma unroll
            for (int mi = 0; mi < 4; ++mi)
#pragma unroll
                for (int ni = 0; ni < 4; ++ni)
                    acc[mi][ni] = __builtin_amdgcn_mfma_f32_16x16x32_bf16(
                        af[mi], bfr[ni], acc[mi][ni], 0, 0, 0);
        }
    }

    // ---- epilogue: acc -> LDS (bf16, swizzled) -> coalesced 16B stores ----
    __syncthreads();  // all ds_reads complete before overwrite
    // C/D layout: col = lane&15, row = (lane>>4)*4 + reg
#pragma unroll
    for (int mi = 0; mi < 4; ++mi)
#pragma unroll
        for (int ni = 0; ni < 4; ++ni) {
            int col = wn + ni * 16 + lr;
#pragma unroll
            for (int rg = 0; rg < 4; ++rg) {
                int row = wm + mi * 16 + g * 4 + rg;
                int sc = col ^ (((row >> 2) & 3) << 4);
                smem[row * 128 + sc] = f2b(acc[mi][ni][rg]);
            }
        }
    __syncthreads();
#pragma unroll
    for (int p = 0; p < 8; ++p) {
        int cid = p * 256 + t;          // 0..2047
        int row = cid >> 4;             // 0..127
        int c0 = (cid & 15) * 8;        // 0..120
        int sc0 = c0 ^ (((row >> 2) & 3) << 4);
        short8 vv = *(const short8*)&smem[row * 128 + sc0];
        *(short8*)&Y[(size_t)(m0 + row) * 768 + n0 + c0] = vv;
    }
}

// ---- attention: 2 pixels per wave; lane owns 8 channels (head = (lane&31)>>2) ----
__global__ __launch_bounds__(256) void attn3(const ushortT* __restrict__ qkv,
                                             float* __restrict__ out) {
    const float scale = 0.17677669529663689f;  // 1/sqrt(32)
    int bid = blockIdx.x;
    int sbid = (bid & 7) * 512 + (bid >> 3);   // XCD-chunk swizzle (bijective)
    const int t = threadIdx.x;
    const int wpair = sbid * 4 + (t >> 6);     // 0..16383
    const int half = (t >> 5) & 1;
    const int l = t & 31;                      // lane within pixel
    const int wid = wpair * 2 + half;          // pixel 0..32767
    const int b = wid >> 12, pix = wid & 4095;
    const int h = pix >> 6, w = pix & 63;

    const size_t pbase = (size_t)wid * 768;
    short8 qu = *(const short8*)&qkv[pbase + l * 8];
    float q[8];
#pragma unroll
    for (int c = 0; c < 8; ++c) q[c] = b2f((ushortT)qu[c]) * scale;

    float s[9];
    short8 vu[9];
#pragma unroll
    for (int i = 0; i < 3; ++i) {
#pragma unroll
        for (int j = 0; j < 3; ++j) {
            const int kk = i * 3 + j;
            const int hh = h + (i - 1) * 3;
            const int ww = w + (j - 1) * 3;
            float p = 0.f;
            short8 z = {0, 0, 0, 0, 0, 0, 0, 0};
            vu[kk] = z;
            if ((unsigned)hh < 64u && (unsigned)ww < 64u) {
                const size_t nb = ((size_t)((b << 12) + (hh << 6) + ww)) * 768;
                short8 ku = *(const short8*)&qkv[nb + 256 + l * 8];
                vu[kk] = *(const short8*)&qkv[nb + 512 + l * 8];
#pragma unroll
                for (int c = 0; c < 8; ++c) p = fmaf(q[c], b2f((ushortT)ku[c]), p);
            }
            p += __shfl_xor(p, 1);
            p += __shfl_xor(p, 2);  // 4-lane (one head) reduce
            s[kk] = p;
        }
    }

    float m = s[0];
#pragma unroll
    for (int kk = 1; kk < 9; ++kk) m = fmaxf(m, s[kk]);
    float denom = 0.f;
    float o[8] = {};
#pragma unroll
    for (int kk = 0; kk < 9; ++kk) {
        float e = __expf(s[kk] - m);
        denom += e;
#pragma unroll
        for (int c = 0; c < 8; ++c) o[c] = fmaf(e, b2f((ushortT)vu[kk][c]), o[c]);
    }
    const float inv = 1.0f / denom;
    float* op = &out[(size_t)wid * 256 + l * 8];
    float4 o0 = make_float4(o[0] * inv, o[1] * inv, o[2] * inv, o[3] * inv);
    float4 o1 = make_float4(o[4] * inv, o[5] * inv, o[6] * inv, o[7] * inv);
    *(float4*)op = o0;
    *(float4*)(op + 4) = o1;
}

extern "C" void kernel_launch(void* const* d_in, const int* in_sizes, int n_in,
                              void* d_out, int out_size, void* d_ws, size_t ws_size,
                              hipStream_t stream) {
    const float* x  = (const float*)d_in[0];   // [8,64,64,256] f32
    const float* Wq = (const float*)d_in[1];   // [768,256] f32
    float* out = (float*)d_out;                // [8,64,64,256] f32

    ushortT* wb  = (ushortT*)d_ws;             // [768,256]  bf16
    ushortT* qkv = wb + (size_t)196608;        // [32768,768] bf16

    wcvt<<<192, 256, 0, stream>>>(Wq, wb);
    gemm_qkv<<<1536, 256, 0, stream>>>(x, wb, qkv);
    attn3<<<4096, 256, 0, stream>>>(qkv, out);
}